// Round 6
// baseline (229.631 us; speedup 1.0000x reference)
//
#include <hip/hip_runtime.h>
#include <math.h>

// x fp32 [B=8, C=64, S=32*128*128=524288]
// norm over C, avg+max over S, relu, sigmoid(out^2) -> [B,C]
typedef float f32x4 __attribute__((ext_vector_type(4)));

#define NC     64
#define NS     524288
#define NB     8
#define NW     16              // waves per block (1024 threads)
#define GP     1024            // positions per group (= block threads)
#define GROUPS 2               // groups per block
#define BPB    256             // blocks per batch = NS/(GROUPS*GP)

// Group-of-1024 structure:
//  - wave w owns channels 4w..4w+3; lane k owns positions {4k+256j, j=0..3}
//  - per group: 16 NT float4 loads (4 KB sequential per channel stream,
//    offsets imm-folded), one nsq row write, barrier,
//    per-POSITION column reduce (thread t = position t: 16 b32 reads,
//    ONE rsqrt), barrier, normalize from held registers.
//  - 2 barriers/group (4/block vs round-5's 8), ~4x less LDS read traffic,
//    16x fewer rsqrt. Single nsq buffer is race-free: col-reads of group g
//    finish before B2(g); g+1 writes happen after B2(g). rnorm reads of g
//    finish before B1(g+1); rnorm writes of g+1 happen after B1(g+1).
__global__ __launch_bounds__(1024)
void ca_partial(const float* __restrict__ x, float* __restrict__ ws) {
    __shared__ float nsq_s[NW][GP];   // 64 KB
    __shared__ float rnorm_s[GP];     // 4 KB

    const int b   = blockIdx.y;
    const int blk = blockIdx.x;
    const int t   = threadIdx.x;
    const int w   = t >> 6;     // wave id 0..15
    const int k   = t & 63;     // lane

    float run_sum[4], run_max[4];
    #pragma unroll
    for (int i = 0; i < 4; ++i) { run_sum[i] = 0.0f; run_max[i] = -INFINITY; }

    // wave w's channel-0 pointer at this block's first group, lane offset 4k
    const float* base = x + (size_t)b * NC * NS + (size_t)(4 * w) * NS
                          + (size_t)blk * GROUPS * GP + 4 * k;

    #pragma unroll
    for (int grp = 0; grp < GROUPS; ++grp) {
        const float* gbase = base + grp * GP;

        // ---- load 4 channels x 4 consecutive float4 (4 KB/stream, NT) ----
        f32x4 v[4][4];                 // [channel i][subchunk j], const-indexed
        #pragma unroll
        for (int i = 0; i < 4; ++i) {
            const float* ci = gbase + (size_t)i * NS;
            #pragma unroll
            for (int j = 0; j < 4; ++j)
                v[i][j] = __builtin_nontemporal_load(
                              reinterpret_cast<const f32x4*>(ci + 256 * j));
        }

        // ---- per-position nsq partial (this wave's 4 channels) ----
        #pragma unroll
        for (int j = 0; j < 4; ++j) {
            f32x4 n = v[0][j] * v[0][j];
            n += v[1][j] * v[1][j];
            n += v[2][j] * v[2][j];
            n += v[3][j] * v[3][j];
            *reinterpret_cast<f32x4*>(&nsq_s[w][4 * k + 256 * j]) = n;
        }
        __syncthreads();               // B1: nsq rows visible

        // ---- column reduce: thread t owns position t (one rsqrt each) ----
        float s16 = 0.0f;
        #pragma unroll
        for (int ww = 0; ww < NW; ++ww) s16 += nsq_s[ww][t];
        rnorm_s[t] = 1.0f / fmaxf(sqrtf(s16), 1e-12f);
        __syncthreads();               // B2: rnorm visible

        // ---- normalize held registers, accumulate per-channel sum/max ----
        #pragma unroll
        for (int j = 0; j < 4; ++j) {
            const f32x4 rn = *reinterpret_cast<const f32x4*>(&rnorm_s[4 * k + 256 * j]);
            #pragma unroll
            for (int i = 0; i < 4; ++i) {
                const f32x4 xn = v[i][j] * rn;
                run_sum[i] += (xn.x + xn.y) + (xn.z + xn.w);
                run_max[i] = fmaxf(run_max[i],
                                   fmaxf(fmaxf(xn.x, xn.y), fmaxf(xn.z, xn.w)));
            }
        }
    }

    // ---- one-time wave butterfly reduce, lane 0 writes partials ----
    float* wp = ws + (size_t)(b * BPB + blk) * (2 * NC);
    #pragma unroll
    for (int i = 0; i < 4; ++i) {
        float s = run_sum[i];
        float m = run_max[i];
        #pragma unroll
        for (int d = 32; d > 0; d >>= 1) {
            s += __shfl_xor(s, d, 64);
            m = fmaxf(m, __shfl_xor(m, d, 64));
        }
        if (k == 0) {
            wp[4 * w + i]      = s;   // channel c = 4w+i
            wp[NC + 4 * w + i] = m;
        }
    }
}

// Reduce BPB partials per (b,c), apply relu + sigmoid(out^2).
__global__ __launch_bounds__(1024)
void ca_final(const float* __restrict__ ws, float* __restrict__ out) {
    __shared__ float fs[16][NC];
    __shared__ float fm[16][NC];

    const int b = blockIdx.x;
    const int t = threadIdx.x;
    const int c = t & 63;
    const int q = t >> 6;      // 0..15

    float s = 0.0f, m = -INFINITY;
    for (int blk = q; blk < BPB; blk += 16) {
        const float* w = ws + (size_t)(b * BPB + blk) * (2 * NC);
        s += w[c];
        m = fmaxf(m, w[NC + c]);
    }
    fs[q][c] = s;
    fm[q][c] = m;
    __syncthreads();

    if (t < NC) {
        float ts = 0.0f, tm = -INFINITY;
        #pragma unroll
        for (int q2 = 0; q2 < 16; ++q2) {
            ts += fs[q2][t];
            tm = fmaxf(tm, fm[q2][t]);
        }
        float avg = ts * (1.0f / (float)NS);
        float o   = fmaxf(avg + tm, 0.0f);
        float att = 1.0f / (1.0f + expf(-o * o));
        out[b * NC + t] = att;
    }
}

extern "C" void kernel_launch(void* const* d_in, const int* in_sizes, int n_in,
                              void* d_out, int out_size, void* d_ws, size_t ws_size,
                              hipStream_t stream) {
    const float* x = (const float*)d_in[0];
    float* ws  = (float*)d_ws;
    float* out = (float*)d_out;

    dim3 grid1(BPB, NB);
    ca_partial<<<grid1, 1024, 0, stream>>>(x, ws);
    ca_final<<<NB, 1024, 0, stream>>>(ws, out);
}